// Round 5
// baseline (202.511 us; speedup 1.0000x reference)
//
#include <hip/hip_runtime.h>
#include <math.h>

#define NCLS 16
#define TILE 32
#define PAD  36      // 144 B row pitch: every row 16B-aligned for ds_read_b128
#define NB   2048
#define PIXB 64      // pixels per norm block (16 dim-lanes x 16 float4 pixel-groups)

// global float4 loads at 4-byte-aligned addresses (class start is arbitrary)
typedef float vfloat4 __attribute__((ext_vector_type(4), aligned(4)));

struct Ctl {
    int   counts[NCLS];
    int   starts[NCLS + 1];
    int   tpc[NCLS];          // tiles per class dimension = ceil(n/TILE)
    int   pairBase[NCLS + 1]; // prefix sum of tpc^2
    float classSum[NCLS];
};

// ---------------- Kernel 1: norms (float4 over pixels) + ctl ----------------
// gt is SORTED -> class boundaries via binary search; contiguous segments == classes.
__global__ __launch_bounds__(256) void prep_kernel(
    const float* __restrict__ P, const float* __restrict__ T,
    const int* __restrict__ gt, int V, int D,
    Ctl* __restrict__ ctl,
    float* __restrict__ normP, float* __restrict__ normT,
    int nbNorm) {
    const int b = blockIdx.x;
    const int t = threadIdx.x;
    if (b < nbNorm) {
        __shared__ vfloat4 sP[16][17], sT[16][17];
        const int g    = t & 15;       // pixel group: pixels 4g..4g+3
        const int dl   = t >> 4;       // dim lane 0..15
        const int base = b * PIXB;
        vfloat4 np4 = {0.f, 0.f, 0.f, 0.f};
        vfloat4 nt4 = {0.f, 0.f, 0.f, 0.f};
        if (base + 4 * g + 3 < V) {
            for (int d = dl; d < D; d += 16) {
                long idx = (long)d * V + base + 4 * g;
                vfloat4 x = *(const vfloat4*)&P[idx];
                vfloat4 y = *(const vfloat4*)&T[idx];
                np4 += x * x;
                nt4 += y * y;
            }
        } else {
            for (int d = dl; d < D; d += 16) {
                long idx = (long)d * V + base + 4 * g;
                #pragma unroll
                for (int k = 0; k < 4; ++k) {
                    if (base + 4 * g + k < V) {
                        float x = P[idx + k], y = T[idx + k];
                        np4[k] += x * x; nt4[k] += y * y;
                    }
                }
            }
        }
        sP[dl][g] = np4; sT[dl][g] = nt4;
        __syncthreads();
        if (t < PIXB && base + t < V) {
            const int gg = t >> 2, cc = t & 3;
            float sp = 0.f, st = 0.f;
            #pragma unroll
            for (int k = 0; k < 16; ++k) { sp += sP[k][gg][cc]; st += sT[k][gg][cc]; }
            normP[base + t] = sp;
            normT[base + t] = st;
        }
    } else {
        if (t < NCLS) {
            int lo = 0, hi = V;            // lower_bound of class id t
            while (lo < hi) {
                int mid = (lo + hi) >> 1;
                if (gt[mid] < t) lo = mid + 1; else hi = mid;
            }
            ctl->starts[t] = lo;
            ctl->classSum[t] = 0.0f;       // ws is poisoned 0xAA each replay
        }
        if (t == 0) ctl->starts[NCLS] = V;
        __syncthreads();
        if (t == 0) {
            int pb = 0;
            for (int c = 0; c < NCLS; ++c) {
                int n = ctl->starts[c + 1] - ctl->starts[c];
                ctl->counts[c] = n;
                int tp = (n + TILE - 1) / TILE;
                ctl->tpc[c] = tp;
                ctl->pairBase[c] = pb;
                pb += tp * tp;
            }
            ctl->pairBase[NCLS] = pb;
        }
    }
}

// ---------------- Kernel 2: balanced flat list of 32x32 pair tiles ----------
// dist(i,j) = n_i + n_j - 2<x_i,x_j>  (Gram form, matches reference numerics)
// Register-prefetched D-chunks: global loads for chunk k+1 issue before the
// compute of chunk k, hiding ~600-900 cyc HBM/L2 latency behind ~770 cyc VALU.
__global__ __launch_bounds__(256, 4) void mmd_kernel(
    const float* __restrict__ P, const float* __restrict__ T,
    int V, int D, const Ctl* __restrict__ ctl,
    const float* __restrict__ normP, const float* __restrict__ normT,
    float* __restrict__ classSum)
{
    __shared__ float sPr[TILE][PAD], sTr[TILE][PAD];
    __shared__ float sPc[TILE][PAD], sTc[TILE][PAD];
    __shared__ float wsum[4];

    const int t  = threadIdx.x;
    const int tx = t & 15;   // cols tx, tx+16  (banks (4tx+dg)%32 -> 2-way, free)
    const int ty = t >> 4;   // rows ty, ty+16
    const int W  = ctl->pairBase[NCLS];

    // staging decode: bijection t -> (d, r4); write banks 2-way max (free).
    const int sd  = (t >> 2) & 31;
    const int sr4 = ((t & 3) << 2) | ((t >> 7) << 4);

    const float invs[6] = {-0.25f, -0.1f, -0.05f, -0.025f, -0.0125f, -1.0f/120.0f};

    for (int w = blockIdx.x; w < W; w += gridDim.x) {
        int c = 0;
        while (ctl->pairBase[c + 1] <= w) ++c;
        const int local = w - ctl->pairBase[c];
        const int tp    = ctl->tpc[c];
        const int ti    = local / tp;
        const int tj    = local - ti * tp;
        const int n     = ctl->counts[c];
        const int start = ctl->starts[c];
        const int i0    = ti * TILE;
        const int j0    = tj * TILE;

        // epilogue norms: issue now, consumed after the chunk loop (hidden)
        const float nPi0 = normP[start + min(i0 + ty,      n - 1)];
        const float nPi1 = normP[start + min(i0 + ty + 16, n - 1)];
        const float nTi0 = normT[start + min(i0 + ty,      n - 1)];
        const float nTi1 = normT[start + min(i0 + ty + 16, n - 1)];
        const float nPj0 = normP[start + min(j0 + tx,      n - 1)];
        const float nPj1 = normP[start + min(j0 + tx + 16, n - 1)];
        const float nTj0 = normT[start + min(j0 + tx,      n - 1)];
        const float nTj1 = normT[start + min(j0 + tx + 16, n - 1)];

        const int ibase = i0 + sr4;
        const int jbase = j0 + sr4;

        auto issue_loads = [&](int dcc, vfloat4& vPr, vfloat4& vTr,
                               vfloat4& vPc, vfloat4& vTc) {
            const long off = (long)(dcc + sd) * (long)V + start;
            if (ibase + 3 < n) {
                vPr = *(const vfloat4*)&P[off + ibase];
                vTr = *(const vfloat4*)&T[off + ibase];
            } else {
                int a0 = min(ibase, n-1), a1 = min(ibase+1, n-1);
                int a2 = min(ibase+2, n-1), a3 = min(ibase+3, n-1);
                vPr = (vfloat4){P[off+a0], P[off+a1], P[off+a2], P[off+a3]};
                vTr = (vfloat4){T[off+a0], T[off+a1], T[off+a2], T[off+a3]};
            }
            if (jbase + 3 < n) {
                vPc = *(const vfloat4*)&P[off + jbase];
                vTc = *(const vfloat4*)&T[off + jbase];
            } else {
                int a0 = min(jbase, n-1), a1 = min(jbase+1, n-1);
                int a2 = min(jbase+2, n-1), a3 = min(jbase+3, n-1);
                vPc = (vfloat4){P[off+a0], P[off+a1], P[off+a2], P[off+a3]};
                vTc = (vfloat4){T[off+a0], T[off+a1], T[off+a2], T[off+a3]};
            }
        };

        float dpp[2][2] = {{0.f,0.f},{0.f,0.f}};
        float dtt[2][2] = {{0.f,0.f},{0.f,0.f}};
        float dpt[2][2] = {{0.f,0.f},{0.f,0.f}};

        vfloat4 vPr, vTr, vPc, vTc;
        issue_loads(0, vPr, vTr, vPc, vTc);

        for (int dc = 0; dc < D; dc += TILE) {
            __syncthreads();   // previous chunk's LDS reads (and wsum) complete
            #pragma unroll
            for (int k = 0; k < 4; ++k) {
                sPr[sr4 + k][sd] = vPr[k];
                sTr[sr4 + k][sd] = vTr[k];
                sPc[sr4 + k][sd] = vPc[k];
                sTc[sr4 + k][sd] = vTc[k];
            }
            __syncthreads();
            if (dc + TILE < D)                      // prefetch next chunk now;
                issue_loads(dc + TILE, vPr, vTr, vPc, vTc);  // overlaps compute

            #pragma unroll
            for (int dg = 0; dg < TILE; dg += 4) {
                float4 pr0 = *(const float4*)&sPr[ty     ][dg];
                float4 pr1 = *(const float4*)&sPr[ty + 16][dg];
                float4 tr0 = *(const float4*)&sTr[ty     ][dg];
                float4 tr1 = *(const float4*)&sTr[ty + 16][dg];
                float4 pc0 = *(const float4*)&sPc[tx     ][dg];
                float4 pc1 = *(const float4*)&sPc[tx + 16][dg];
                float4 tc0 = *(const float4*)&sTc[tx     ][dg];
                float4 tc1 = *(const float4*)&sTc[tx + 16][dg];

                dpp[0][0] += pr0.x*pc0.x + pr0.y*pc0.y + pr0.z*pc0.z + pr0.w*pc0.w;
                dpp[0][1] += pr0.x*pc1.x + pr0.y*pc1.y + pr0.z*pc1.z + pr0.w*pc1.w;
                dpp[1][0] += pr1.x*pc0.x + pr1.y*pc0.y + pr1.z*pc0.z + pr1.w*pc0.w;
                dpp[1][1] += pr1.x*pc1.x + pr1.y*pc1.y + pr1.z*pc1.z + pr1.w*pc1.w;

                dtt[0][0] += tr0.x*tc0.x + tr0.y*tc0.y + tr0.z*tc0.z + tr0.w*tc0.w;
                dtt[0][1] += tr0.x*tc1.x + tr0.y*tc1.y + tr0.z*tc1.z + tr0.w*tc1.w;
                dtt[1][0] += tr1.x*tc0.x + tr1.y*tc0.y + tr1.z*tc0.z + tr1.w*tc0.w;
                dtt[1][1] += tr1.x*tc1.x + tr1.y*tc1.y + tr1.z*tc1.z + tr1.w*tc1.w;

                dpt[0][0] += pr0.x*tc0.x + pr0.y*tc0.y + pr0.z*tc0.z + pr0.w*tc0.w;
                dpt[0][1] += pr0.x*tc1.x + pr0.y*tc1.y + pr0.z*tc1.z + pr0.w*tc1.w;
                dpt[1][0] += pr1.x*tc0.x + pr1.y*tc0.y + pr1.z*tc0.z + pr1.w*tc0.w;
                dpt[1][1] += pr1.x*tc1.x + pr1.y*tc1.y + pr1.z*tc1.z + pr1.w*tc1.w;
            }
        }

        // epilogue: distances via Gram form, 6-bandwidth RBF sum
        float total = 0.0f;
        const float nPi[2] = {nPi0, nPi1}, nTi[2] = {nTi0, nTi1};
        const float nPj[2] = {nPj0, nPj1}, nTj[2] = {nTj0, nTj1};
        #pragma unroll
        for (int a = 0; a < 2; ++a) {
            #pragma unroll
            for (int b2 = 0; b2 < 2; ++b2) {
                int ii = i0 + ty + 16*a;
                int jj = j0 + tx + 16*b2;
                if (ii < n && jj < n) {
                    float Dpp = nPi[a] + nPj[b2] - 2.0f * dpp[a][b2];
                    float Dtt = nTi[a] + nTj[b2] - 2.0f * dtt[a][b2];
                    float Dpt = nPi[a] + nTj[b2] - 2.0f * dpt[a][b2];
                    #pragma unroll
                    for (int s = 0; s < 6; ++s) {
                        total += __expf(invs[s] * Dpp)
                               + __expf(invs[s] * Dtt)
                               - 2.0f * __expf(invs[s] * Dpt);
                    }
                }
            }
        }

        // wave shuffle reduce (width 64), 4 wave leaders via LDS, 1 atomic
        #pragma unroll
        for (int off = 32; off > 0; off >>= 1)
            total += __shfl_down(total, off, 64);
        if ((t & 63) == 0) wsum[t >> 6] = total;
        __syncthreads();
        if (t == 0)
            atomicAdd(&classSum[c], wsum[0] + wsum[1] + wsum[2] + wsum[3]);
    }
}

// ---------------- Kernel 3: finalize scalar loss ----------------------------
__global__ void finalize_kernel(const int* __restrict__ counts,
                                const float* __restrict__ classSum,
                                float* __restrict__ out) {
    if (threadIdx.x == 0) {
        float loss = 0.0f;
        int k = 0;
        for (int c = 0; c < NCLS; ++c) {
            int n = counts[c];
            if (n > 0) {
                ++k;
                float fn    = (float)n;
                float denom = fmaxf(2.0f * fn * fn, 1.0f);
                float l     = classSum[c] / denom;
                if (l > 0.0f) loss += sqrtf(l);
            }
        }
        out[0] = (k > 0) ? (loss / (float)k) : 0.0f;
    }
}

extern "C" void kernel_launch(void* const* d_in, const int* in_sizes, int n_in,
                              void* d_out, int out_size, void* d_ws, size_t ws_size,
                              hipStream_t stream) {
    const float* predict = (const float*)d_in[0];
    const float* target  = (const float*)d_in[1];
    const int*   gt      = (const int*)d_in[2];
    // d_in[3] = ignore_mask: all-True, unused by the reference math.

    const int V = in_sizes[2];        // B*H*W = 4096
    const int D = in_sizes[0] / V;    // C = 128

    Ctl* ctl = (Ctl*)d_ws;
    size_t normOff = (sizeof(Ctl) + 15) & ~(size_t)15;
    float* normP = (float*)((char*)d_ws + normOff);
    float* normT = normP + V;
    float* classSum = (float*)((char*)d_ws + offsetof(Ctl, classSum));

    int nbNorm = (V + PIXB - 1) / PIXB;
    prep_kernel<<<nbNorm + 1, 256, 0, stream>>>(predict, target, gt, V, D,
                                                ctl, normP, normT, nbNorm);

    mmd_kernel<<<NB, 256, 0, stream>>>(predict, target, V, D, ctl,
                                       normP, normT, classSum);

    finalize_kernel<<<1, 64, 0, stream>>>(ctl->counts, classSum, (float*)d_out);
}

// Round 7
// 170.028 us; speedup vs baseline: 1.1910x; 1.1910x over previous
//
#include <hip/hip_runtime.h>
#include <math.h>

#define NCLS 16
#define TS   64      // pair-tile side (64x64 pairs per work item)
#define CH   32      // D-chunk depth
#define PAD  36      // 144 B row pitch: every row 16B-aligned for ds_read_b128
#define NB   512
#define PIXB 16      // pixels per norm block

// global float4 loads at 4-byte-aligned addresses (class start is arbitrary)
typedef float vfloat4 __attribute__((ext_vector_type(4), aligned(4)));

struct Ctl {
    int   counts[NCLS];
    int   starts[NCLS + 1];
    int   tpc[NCLS];          // tiles per class dimension = ceil(n/TS)
    int   pairBase[NCLS + 1]; // prefix sum of tpc^2
    float classSum[NCLS];
};

// ---------------- Kernel 1: norms (16 px/block, 257 blocks) + ctl -----------
// gt is SORTED -> class boundaries via binary search; contiguous segments == classes.
__global__ __launch_bounds__(256) void prep_kernel(
    const float* __restrict__ P, const float* __restrict__ T,
    const int* __restrict__ gt, int V, int D,
    Ctl* __restrict__ ctl,
    float* __restrict__ normP, float* __restrict__ normT,
    int nbNorm) {
    const int b = blockIdx.x;
    const int t = threadIdx.x;
    if (b < nbNorm) {
        __shared__ float pP[16][PIXB + 1], pT[16][PIXB + 1];
        const int pix = t & (PIXB - 1);
        const int dl  = t >> 4;           // 0..15
        const int v   = b * PIXB + pix;
        float np = 0.f, nt = 0.f;
        if (v < V) {
            #pragma unroll 4
            for (int d = dl; d < D; d += 16) {
                float x = P[(long)d * V + v]; np += x * x;
                float y = T[(long)d * V + v]; nt += y * y;
            }
        }
        pP[dl][pix] = np; pT[dl][pix] = nt;
        __syncthreads();
        if (t < PIXB && b * PIXB + t < V) {
            float sp = 0.f, st = 0.f;
            #pragma unroll
            for (int k = 0; k < 16; ++k) { sp += pP[k][t]; st += pT[k][t]; }
            normP[b * PIXB + t] = sp;
            normT[b * PIXB + t] = st;
        }
    } else {
        if (t < NCLS) {
            int lo = 0, hi = V;            // lower_bound of class id t
            while (lo < hi) {
                int mid = (lo + hi) >> 1;
                if (gt[mid] < t) lo = mid + 1; else hi = mid;
            }
            ctl->starts[t] = lo;
            ctl->classSum[t] = 0.0f;       // ws is poisoned 0xAA each replay
        }
        if (t == 0) ctl->starts[NCLS] = V;
        __syncthreads();
        if (t == 0) {
            int pb = 0;
            for (int c = 0; c < NCLS; ++c) {
                int n = ctl->starts[c + 1] - ctl->starts[c];
                ctl->counts[c] = n;
                int tp = (n + TS - 1) / TS;
                ctl->tpc[c] = tp;
                ctl->pairBase[c] = pb;
                pb += tp * tp;
            }
            ctl->pairBase[NCLS] = pb;
        }
    }
}

// ---------------- Kernel 2: 64x64 pair tiles, 4x4 per thread ----------------
// dist(i,j) = n_i + n_j - 2<x_i,x_j>  (Gram form, matches reference numerics).
// Staging tail rule (R6 bug fix): a quad is vector-loaded ONLY if fully inside
// the class; otherwise each element clamps to pixel n-1. Thus every row r < n
// holds exactly pixel r's data (norm/dot always consistent -- the RBF exp
// amplifies any mismatch catastrophically), and rows r >= n hold pixel n-1's
// data, which the ii<n / jj<n epilogue guard masks.
__global__ __launch_bounds__(256) void mmd_kernel(
    const float* __restrict__ P, const float* __restrict__ T,
    int V, int D, const Ctl* __restrict__ ctl,
    const float* __restrict__ normP, const float* __restrict__ normT,
    float* __restrict__ classSum)
{
    __shared__ float sPr[TS][PAD], sTr[TS][PAD];
    __shared__ float sPc[TS][PAD], sTc[TS][PAD];
    __shared__ float wsum[4];

    const int t  = threadIdx.x;
    const int tx = t & 15;   // cols tx + 16b, b=0..3
    const int ty = t >> 4;   // rows ty + 16a, a=0..3
    const int sd = t >> 3;   // staging dim 0..31
    const int qb = t & 7;    // staging pixel-quad base: quads qb and qb+8
    const int W  = ctl->pairBase[NCLS];

    const float invs[6] = {-0.25f, -0.1f, -0.05f, -0.025f, -0.0125f, -1.0f/120.0f};

    for (int w = blockIdx.x; w < W; w += gridDim.x) {
        int c = 0;
        while (ctl->pairBase[c + 1] <= w) ++c;
        const int local = w - ctl->pairBase[c];
        const int tp    = ctl->tpc[c];
        const int ti    = local / tp;
        const int tj    = local - ti * tp;
        const int n     = ctl->counts[c];
        const int start = ctl->starts[c];
        const int i0    = ti * TS;
        const int j0    = tj * TS;

        // relative quad bases within the class
        const int r0 = i0 + 4 * qb;
        const int r1 = i0 + 4 * qb + 32;
        const int c0 = j0 + 4 * qb;
        const int c1 = j0 + 4 * qb + 32;

        vfloat4 vPr0, vPr1, vTr0, vTr1, vPc0, vPc1, vTc0, vTc1;

        // load one quad (P and T) at class-relative base `rb` for dim-offset
        // `off` (= (dc+sd)*V). Vector path iff quad fully inside the class.
        auto load_quad = [&](long off, int rb, vfloat4& vP, vfloat4& vT) {
            if (rb + 3 < n) {
                vP = *(const vfloat4*)&P[off + start + rb];
                vT = *(const vfloat4*)&T[off + start + rb];
            } else {
                int a0 = start + min(rb,     n - 1);
                int a1 = start + min(rb + 1, n - 1);
                int a2 = start + min(rb + 2, n - 1);
                int a3 = start + min(rb + 3, n - 1);
                vP = (vfloat4){P[off + a0], P[off + a1], P[off + a2], P[off + a3]};
                vT = (vfloat4){T[off + a0], T[off + a1], T[off + a2], T[off + a3]};
            }
        };
        auto issue_loads = [&](int dcc) {
            const long off = (long)(dcc + sd) * (long)V;
            load_quad(off, r0, vPr0, vTr0);
            load_quad(off, r1, vPr1, vTr1);
            load_quad(off, c0, vPc0, vTc0);
            load_quad(off, c1, vPc1, vTc1);
        };

        float dpp[4][4], dtt[4][4], dpt[4][4];
        #pragma unroll
        for (int a = 0; a < 4; ++a)
            #pragma unroll
            for (int b = 0; b < 4; ++b) { dpp[a][b] = 0.f; dtt[a][b] = 0.f; dpt[a][b] = 0.f; }

        issue_loads(0);

        for (int dc = 0; dc < D; dc += CH) {
            __syncthreads();   // previous chunk's LDS reads (and wsum) complete
            #pragma unroll
            for (int k = 0; k < 4; ++k) {
                sPr[4*qb +      k][sd] = vPr0[k];
                sPr[4*qb + 32 + k][sd] = vPr1[k];
                sTr[4*qb +      k][sd] = vTr0[k];
                sTr[4*qb + 32 + k][sd] = vTr1[k];
                sPc[4*qb +      k][sd] = vPc0[k];
                sPc[4*qb + 32 + k][sd] = vPc1[k];
                sTc[4*qb +      k][sd] = vTc0[k];
                sTc[4*qb + 32 + k][sd] = vTc1[k];
            }
            __syncthreads();
            if (dc + CH < D)
                issue_loads(dc + CH);   // prefetch next chunk; overlaps compute

            #pragma unroll
            for (int dg = 0; dg < CH; dg += 4) {
                float4 rP[4], rT[4], cP[4], cT[4];
                #pragma unroll
                for (int a = 0; a < 4; ++a) {
                    rP[a] = *(const float4*)&sPr[ty + 16*a][dg];
                    rT[a] = *(const float4*)&sTr[ty + 16*a][dg];
                    cP[a] = *(const float4*)&sPc[tx + 16*a][dg];
                    cT[a] = *(const float4*)&sTc[tx + 16*a][dg];
                }
                #pragma unroll
                for (int a = 0; a < 4; ++a) {
                    #pragma unroll
                    for (int b = 0; b < 4; ++b) {
                        dpp[a][b] += rP[a].x*cP[b].x + rP[a].y*cP[b].y
                                   + rP[a].z*cP[b].z + rP[a].w*cP[b].w;
                        dtt[a][b] += rT[a].x*cT[b].x + rT[a].y*cT[b].y
                                   + rT[a].z*cT[b].z + rT[a].w*cT[b].w;
                        dpt[a][b] += rP[a].x*cT[b].x + rP[a].y*cT[b].y
                                   + rP[a].z*cT[b].z + rP[a].w*cT[b].w;
                    }
                }
            }
        }

        // epilogue: distances via Gram form, 6-bandwidth RBF sum (masked)
        float total = 0.0f;
        #pragma unroll
        for (int a = 0; a < 4; ++a) {
            const int ii = i0 + ty + 16*a;
            if (ii < n) {
                const float nPi = normP[start + ii];
                const float nTi = normT[start + ii];
                #pragma unroll
                for (int b = 0; b < 4; ++b) {
                    const int jj = j0 + tx + 16*b;
                    if (jj < n) {
                        const float nPj = normP[start + jj];
                        const float nTj = normT[start + jj];
                        float Dpp = nPi + nPj - 2.0f * dpp[a][b];
                        float Dtt = nTi + nTj - 2.0f * dtt[a][b];
                        float Dpt = nPi + nTj - 2.0f * dpt[a][b];
                        #pragma unroll
                        for (int s = 0; s < 6; ++s) {
                            total += __expf(invs[s] * Dpp)
                                   + __expf(invs[s] * Dtt)
                                   - 2.0f * __expf(invs[s] * Dpt);
                        }
                    }
                }
            }
        }

        // wave shuffle reduce (width 64), 4 wave leaders via LDS, 1 atomic
        #pragma unroll
        for (int off = 32; off > 0; off >>= 1)
            total += __shfl_down(total, off, 64);
        if ((t & 63) == 0) wsum[t >> 6] = total;
        __syncthreads();
        if (t == 0)
            atomicAdd(&classSum[c], wsum[0] + wsum[1] + wsum[2] + wsum[3]);
    }
}

// ---------------- Kernel 3: finalize scalar loss ----------------------------
__global__ void finalize_kernel(const int* __restrict__ counts,
                                const float* __restrict__ classSum,
                                float* __restrict__ out) {
    if (threadIdx.x == 0) {
        float loss = 0.0f;
        int k = 0;
        for (int c = 0; c < NCLS; ++c) {
            int n = counts[c];
            if (n > 0) {
                ++k;
                float fn    = (float)n;
                float denom = fmaxf(2.0f * fn * fn, 1.0f);
                float l     = classSum[c] / denom;
                if (l > 0.0f) loss += sqrtf(l);
            }
        }
        out[0] = (k > 0) ? (loss / (float)k) : 0.0f;
    }
}

extern "C" void kernel_launch(void* const* d_in, const int* in_sizes, int n_in,
                              void* d_out, int out_size, void* d_ws, size_t ws_size,
                              hipStream_t stream) {
    const float* predict = (const float*)d_in[0];
    const float* target  = (const float*)d_in[1];
    const int*   gt      = (const int*)d_in[2];
    // d_in[3] = ignore_mask: all-True, unused by the reference math.

    const int V = in_sizes[2];        // B*H*W = 4096
    const int D = in_sizes[0] / V;    // C = 128

    Ctl* ctl = (Ctl*)d_ws;
    size_t normOff = (sizeof(Ctl) + 15) & ~(size_t)15;
    float* normP = (float*)((char*)d_ws + normOff);
    float* normT = normP + V;
    float* classSum = (float*)((char*)d_ws + offsetof(Ctl, classSum));

    int nbNorm = (V + PIXB - 1) / PIXB;
    prep_kernel<<<nbNorm + 1, 256, 0, stream>>>(predict, target, gt, V, D,
                                                ctl, normP, normT, nbNorm);

    mmd_kernel<<<NB, 256, 0, stream>>>(predict, target, V, D, ctl,
                                       normP, normT, classSum);

    finalize_kernel<<<1, 64, 0, stream>>>(ctl->counts, classSum, (float*)d_out);
}

// Round 8
// 159.391 us; speedup vs baseline: 1.2705x; 1.0667x over previous
//
#include <hip/hip_runtime.h>
#include <math.h>

#define NCLS 16
#define TS   64      // pair-tile side (64x64 pairs per work item)
#define CH   32      // D-chunk depth
#define PAD  36      // 144 B row pitch: every row 16B-aligned for ds_read_b128
#define NB   512
#define PIXB 16      // pixels per norm block

// global float4 loads at 4-byte-aligned addresses (class start is arbitrary)
typedef float vfloat4 __attribute__((ext_vector_type(4), aligned(4)));

struct Ctl {
    int   counts[NCLS];
    int   starts[NCLS + 1];
    int   tpc[NCLS];          // tiles per class dimension = ceil(n/TS)
    int   pairBase[NCLS + 1]; // prefix sum of tpc^2
    float classSum[NCLS];
};

// ---------------- Kernel 1: norms (16 px/block, 257 blocks) + ctl -----------
// gt is SORTED -> class boundaries via binary search; contiguous segments == classes.
__global__ __launch_bounds__(256) void prep_kernel(
    const float* __restrict__ P, const float* __restrict__ T,
    const int* __restrict__ gt, int V, int D,
    Ctl* __restrict__ ctl,
    float* __restrict__ normP, float* __restrict__ normT,
    int nbNorm) {
    const int b = blockIdx.x;
    const int t = threadIdx.x;
    if (b < nbNorm) {
        __shared__ float pP[16][PIXB + 1], pT[16][PIXB + 1];
        const int pix = t & (PIXB - 1);
        const int dl  = t >> 4;           // 0..15
        const int v   = b * PIXB + pix;
        float np = 0.f, nt = 0.f;
        if (v < V) {
            #pragma unroll 4
            for (int d = dl; d < D; d += 16) {
                float x = P[(long)d * V + v]; np += x * x;
                float y = T[(long)d * V + v]; nt += y * y;
            }
        }
        pP[dl][pix] = np; pT[dl][pix] = nt;
        __syncthreads();
        if (t < PIXB && b * PIXB + t < V) {
            float sp = 0.f, st = 0.f;
            #pragma unroll
            for (int k = 0; k < 16; ++k) { sp += pP[k][t]; st += pT[k][t]; }
            normP[b * PIXB + t] = sp;
            normT[b * PIXB + t] = st;
        }
    } else {
        if (t < NCLS) {
            int lo = 0, hi = V;            // lower_bound of class id t
            while (lo < hi) {
                int mid = (lo + hi) >> 1;
                if (gt[mid] < t) lo = mid + 1; else hi = mid;
            }
            ctl->starts[t] = lo;
            ctl->classSum[t] = 0.0f;       // ws is poisoned 0xAA each replay
        }
        if (t == 0) ctl->starts[NCLS] = V;
        __syncthreads();
        if (t == 0) {
            int pb = 0;
            for (int c = 0; c < NCLS; ++c) {
                int n = ctl->starts[c + 1] - ctl->starts[c];
                ctl->counts[c] = n;
                int tp = (n + TS - 1) / TS;
                ctl->tpc[c] = tp;
                ctl->pairBase[c] = pb;
                pb += tp * tp;
            }
            ctl->pairBase[NCLS] = pb;
        }
    }
}

// ---------------- Kernel 2: 64x64 pair tiles, 4x4 per thread ----------------
// dist(i,j) = n_i + n_j - 2<x_i,x_j>  (Gram form, matches reference numerics).
// Staging tail rule: a quad is vector-loaded ONLY if fully inside the class;
// otherwise per-element clamp to pixel n-1 (rows r<n always hold pixel r's
// data -- RBF exp amplifies any norm/dot mismatch; rows >= n are masked).
// R8: inner loop phased (dpp -> dpt -> dtt) so at most 8 float4 LDS operands
// are live at once; R7's 16-operand version spilled at 256 VGPR (105 MB
// scratch writes = the whole 110 us).
__global__ __launch_bounds__(256) void mmd_kernel(
    const float* __restrict__ P, const float* __restrict__ T,
    int V, int D, const Ctl* __restrict__ ctl,
    const float* __restrict__ normP, const float* __restrict__ normT,
    float* __restrict__ classSum)
{
    __shared__ float sPr[TS][PAD], sTr[TS][PAD];
    __shared__ float sPc[TS][PAD], sTc[TS][PAD];
    __shared__ float wsum[4];

    const int t  = threadIdx.x;
    const int tx = t & 15;   // cols tx + 16b, b=0..3
    const int ty = t >> 4;   // rows ty + 16a, a=0..3
    const int sd = t >> 3;   // staging dim 0..31
    const int qb = t & 7;    // staging pixel-quad base: quads qb and qb+8
    const int W  = ctl->pairBase[NCLS];

    const float invs[6] = {-0.25f, -0.1f, -0.05f, -0.025f, -0.0125f, -1.0f/120.0f};

    for (int w = blockIdx.x; w < W; w += gridDim.x) {
        int c = 0;
        while (ctl->pairBase[c + 1] <= w) ++c;
        const int local = w - ctl->pairBase[c];
        const int tp    = ctl->tpc[c];
        const int ti    = local / tp;
        const int tj    = local - ti * tp;
        const int n     = ctl->counts[c];
        const int start = ctl->starts[c];
        const int i0    = ti * TS;
        const int j0    = tj * TS;

        // relative quad bases within the class
        const int r0 = i0 + 4 * qb;
        const int r1 = i0 + 4 * qb + 32;
        const int c0 = j0 + 4 * qb;
        const int c1 = j0 + 4 * qb + 32;

        vfloat4 vPr0, vPr1, vTr0, vTr1, vPc0, vPc1, vTc0, vTc1;

        auto load_quad = [&](long off, int rb, vfloat4& vP, vfloat4& vT) {
            if (rb + 3 < n) {
                vP = *(const vfloat4*)&P[off + start + rb];
                vT = *(const vfloat4*)&T[off + start + rb];
            } else {
                int a0 = start + min(rb,     n - 1);
                int a1 = start + min(rb + 1, n - 1);
                int a2 = start + min(rb + 2, n - 1);
                int a3 = start + min(rb + 3, n - 1);
                vP = (vfloat4){P[off + a0], P[off + a1], P[off + a2], P[off + a3]};
                vT = (vfloat4){T[off + a0], T[off + a1], T[off + a2], T[off + a3]};
            }
        };
        auto issue_loads = [&](int dcc) {
            const long off = (long)(dcc + sd) * (long)V;
            load_quad(off, r0, vPr0, vTr0);
            load_quad(off, r1, vPr1, vTr1);
            load_quad(off, c0, vPc0, vTc0);
            load_quad(off, c1, vPc1, vTc1);
        };

        float dpp[4][4], dtt[4][4], dpt[4][4];
        #pragma unroll
        for (int a = 0; a < 4; ++a)
            #pragma unroll
            for (int b = 0; b < 4; ++b) { dpp[a][b] = 0.f; dtt[a][b] = 0.f; dpt[a][b] = 0.f; }

        issue_loads(0);

        for (int dc = 0; dc < D; dc += CH) {
            __syncthreads();   // previous chunk's LDS reads (and wsum) complete
            #pragma unroll
            for (int k = 0; k < 4; ++k) {
                sPr[4*qb +      k][sd] = vPr0[k];
                sPr[4*qb + 32 + k][sd] = vPr1[k];
                sTr[4*qb +      k][sd] = vTr0[k];
                sTr[4*qb + 32 + k][sd] = vTr1[k];
                sPc[4*qb +      k][sd] = vPc0[k];
                sPc[4*qb + 32 + k][sd] = vPc1[k];
                sTc[4*qb +      k][sd] = vTc0[k];
                sTc[4*qb + 32 + k][sd] = vTc1[k];
            }
            __syncthreads();
            if (dc + CH < D)
                issue_loads(dc + CH);   // prefetch next chunk; overlaps compute

            // phased inner loop: at most 8 float4 operands live at a time
            #pragma unroll
            for (int dg = 0; dg < CH; dg += 4) {
                // phase A: predict rows x predict cols -> dpp
                float4 rP[4], cX[4];
                #pragma unroll
                for (int a = 0; a < 4; ++a) {
                    rP[a] = *(const float4*)&sPr[ty + 16*a][dg];
                    cX[a] = *(const float4*)&sPc[tx + 16*a][dg];
                }
                #pragma unroll
                for (int a = 0; a < 4; ++a)
                    #pragma unroll
                    for (int b = 0; b < 4; ++b)
                        dpp[a][b] += rP[a].x*cX[b].x + rP[a].y*cX[b].y
                                   + rP[a].z*cX[b].z + rP[a].w*cX[b].w;

                // phase B: predict rows x target cols -> dpt (cX reloaded)
                #pragma unroll
                for (int b = 0; b < 4; ++b)
                    cX[b] = *(const float4*)&sTc[tx + 16*b][dg];
                #pragma unroll
                for (int a = 0; a < 4; ++a)
                    #pragma unroll
                    for (int b = 0; b < 4; ++b)
                        dpt[a][b] += rP[a].x*cX[b].x + rP[a].y*cX[b].y
                                   + rP[a].z*cX[b].z + rP[a].w*cX[b].w;

                // phase C: target rows x target cols -> dtt (rP reloaded)
                #pragma unroll
                for (int a = 0; a < 4; ++a)
                    rP[a] = *(const float4*)&sTr[ty + 16*a][dg];
                #pragma unroll
                for (int a = 0; a < 4; ++a)
                    #pragma unroll
                    for (int b = 0; b < 4; ++b)
                        dtt[a][b] += rP[a].x*cX[b].x + rP[a].y*cX[b].y
                                   + rP[a].z*cX[b].z + rP[a].w*cX[b].w;
            }
        }

        // epilogue: distances via Gram form, 6-bandwidth RBF sum (masked)
        float total = 0.0f;
        #pragma unroll
        for (int a = 0; a < 4; ++a) {
            const int ii = i0 + ty + 16*a;
            if (ii < n) {
                const float nPi = normP[start + ii];
                const float nTi = normT[start + ii];
                #pragma unroll
                for (int b = 0; b < 4; ++b) {
                    const int jj = j0 + tx + 16*b;
                    if (jj < n) {
                        const float nPj = normP[start + jj];
                        const float nTj = normT[start + jj];
                        float Dpp = nPi + nPj - 2.0f * dpp[a][b];
                        float Dtt = nTi + nTj - 2.0f * dtt[a][b];
                        float Dpt = nPi + nTj - 2.0f * dpt[a][b];
                        #pragma unroll
                        for (int s = 0; s < 6; ++s) {
                            total += __expf(invs[s] * Dpp)
                                   + __expf(invs[s] * Dtt)
                                   - 2.0f * __expf(invs[s] * Dpt);
                        }
                    }
                }
            }
        }

        // wave shuffle reduce (width 64), 4 wave leaders via LDS, 1 atomic
        #pragma unroll
        for (int off = 32; off > 0; off >>= 1)
            total += __shfl_down(total, off, 64);
        if ((t & 63) == 0) wsum[t >> 6] = total;
        __syncthreads();
        if (t == 0)
            atomicAdd(&classSum[c], wsum[0] + wsum[1] + wsum[2] + wsum[3]);
    }
}

// ---------------- Kernel 3: finalize scalar loss ----------------------------
__global__ void finalize_kernel(const int* __restrict__ counts,
                                const float* __restrict__ classSum,
                                float* __restrict__ out) {
    if (threadIdx.x == 0) {
        float loss = 0.0f;
        int k = 0;
        for (int c = 0; c < NCLS; ++c) {
            int n = counts[c];
            if (n > 0) {
                ++k;
                float fn    = (float)n;
                float denom = fmaxf(2.0f * fn * fn, 1.0f);
                float l     = classSum[c] / denom;
                if (l > 0.0f) loss += sqrtf(l);
            }
        }
        out[0] = (k > 0) ? (loss / (float)k) : 0.0f;
    }
}

extern "C" void kernel_launch(void* const* d_in, const int* in_sizes, int n_in,
                              void* d_out, int out_size, void* d_ws, size_t ws_size,
                              hipStream_t stream) {
    const float* predict = (const float*)d_in[0];
    const float* target  = (const float*)d_in[1];
    const int*   gt      = (const int*)d_in[2];
    // d_in[3] = ignore_mask: all-True, unused by the reference math.

    const int V = in_sizes[2];        // B*H*W = 4096
    const int D = in_sizes[0] / V;    // C = 128

    Ctl* ctl = (Ctl*)d_ws;
    size_t normOff = (sizeof(Ctl) + 15) & ~(size_t)15;
    float* normP = (float*)((char*)d_ws + normOff);
    float* normT = normP + V;
    float* classSum = (float*)((char*)d_ws + offsetof(Ctl, classSum));

    int nbNorm = (V + PIXB - 1) / PIXB;
    prep_kernel<<<nbNorm + 1, 256, 0, stream>>>(predict, target, gt, V, D,
                                                ctl, normP, normT, nbNorm);

    mmd_kernel<<<NB, 256, 0, stream>>>(predict, target, V, D, ctl,
                                       normP, normT, classSum);

    finalize_kernel<<<1, 64, 0, stream>>>(ctl->counts, classSum, (float*)d_out);
}

// Round 9
// 104.090 us; speedup vs baseline: 1.9455x; 1.5313x over previous
//
#include <hip/hip_runtime.h>
#include <math.h>

#define NCLS 16
#define TS   64      // pair-tile side (64x64 pairs per work item)
#define CH   32      // D-chunk depth
#define PAD  36      // 144 B row pitch: every row 16B-aligned for ds_read_b128
#define NB   512
#define PIXB 16      // pixels per norm block

// global float4 loads at 4-byte-aligned addresses (class start is arbitrary)
typedef float vfloat4 __attribute__((ext_vector_type(4), aligned(4)));

struct Ctl {
    int   counts[NCLS];
    int   starts[NCLS + 1];
    int   tpc[NCLS];          // tiles per class dimension = ceil(n/TS)
    int   pairBase[NCLS + 1]; // prefix sum of tpc^2
    float classSum[NCLS];
};

// ---------------- Kernel 1: norms (16 px/block, 257 blocks) + ctl -----------
// gt is SORTED -> class boundaries via binary search; contiguous segments == classes.
__global__ __launch_bounds__(256) void prep_kernel(
    const float* __restrict__ P, const float* __restrict__ T,
    const int* __restrict__ gt, int V, int D,
    Ctl* __restrict__ ctl,
    float* __restrict__ normP, float* __restrict__ normT,
    int nbNorm) {
    const int b = blockIdx.x;
    const int t = threadIdx.x;
    if (b < nbNorm) {
        __shared__ float pP[16][PIXB + 1], pT[16][PIXB + 1];
        const int pix = t & (PIXB - 1);
        const int dl  = t >> 4;           // 0..15
        const int v   = b * PIXB + pix;
        float np = 0.f, nt = 0.f;
        if (v < V) {
            #pragma unroll 4
            for (int d = dl; d < D; d += 16) {
                float x = P[(long)d * V + v]; np += x * x;
                float y = T[(long)d * V + v]; nt += y * y;
            }
        }
        pP[dl][pix] = np; pT[dl][pix] = nt;
        __syncthreads();
        if (t < PIXB && b * PIXB + t < V) {
            float sp = 0.f, st = 0.f;
            #pragma unroll
            for (int k = 0; k < 16; ++k) { sp += pP[k][t]; st += pT[k][t]; }
            normP[b * PIXB + t] = sp;
            normT[b * PIXB + t] = st;
        }
    } else {
        if (t < NCLS) {
            int lo = 0, hi = V;            // lower_bound of class id t
            while (lo < hi) {
                int mid = (lo + hi) >> 1;
                if (gt[mid] < t) lo = mid + 1; else hi = mid;
            }
            ctl->starts[t] = lo;
            ctl->classSum[t] = 0.0f;       // ws is poisoned 0xAA each replay
        }
        if (t == 0) ctl->starts[NCLS] = V;
        __syncthreads();
        if (t == 0) {
            int pb = 0;
            for (int c = 0; c < NCLS; ++c) {
                int n = ctl->starts[c + 1] - ctl->starts[c];
                ctl->counts[c] = n;
                int tp = (n + TS - 1) / TS;
                ctl->tpc[c] = tp;
                ctl->pairBase[c] = pb;
                pb += tp * tp;
            }
            ctl->pairBase[NCLS] = pb;
        }
    }
}

// ---------------- Kernel 2: 64x64 pair tiles, 4x4 per thread ----------------
// dist(i,j) = n_i + n_j - 2<x_i,x_j>  (Gram form, matches reference numerics).
// Staging tail rule: a quad is vector-loaded ONLY if fully inside the class;
// otherwise per-element clamp to pixel n-1 (rows r<n always hold pixel r's
// data -- RBF exp amplifies any norm/dot mismatch; rows >= n are masked).
// R9: `#pragma unroll 1` on BOTH the dc and dg loops. R7/R8 spilled at 256
// VGPR because full unroll let the scheduler hoist up to 192 ds_read_b128,
// stretching operand live ranges; bounding the unroll bounds the live set
// (~48 acc + 32 prefetch + <=64 operands ~= 160 VGPR, no spill). Register
// pressure is governed by what the SCHEDULER may reorder, not source order.
__global__ __launch_bounds__(256) void mmd_kernel(
    const float* __restrict__ P, const float* __restrict__ T,
    int V, int D, const Ctl* __restrict__ ctl,
    const float* __restrict__ normP, const float* __restrict__ normT,
    float* __restrict__ classSum)
{
    __shared__ float sPr[TS][PAD], sTr[TS][PAD];
    __shared__ float sPc[TS][PAD], sTc[TS][PAD];
    __shared__ float wsum[4];

    const int t  = threadIdx.x;
    const int tx = t & 15;   // cols tx + 16b, b=0..3
    const int ty = t >> 4;   // rows ty + 16a, a=0..3
    const int sd = t >> 3;   // staging dim 0..31
    const int qb = t & 7;    // staging pixel-quad base: quads qb and qb+8
    const int W  = ctl->pairBase[NCLS];

    const float invs[6] = {-0.25f, -0.1f, -0.05f, -0.025f, -0.0125f, -1.0f/120.0f};

    for (int w = blockIdx.x; w < W; w += gridDim.x) {
        int c = 0;
        while (ctl->pairBase[c + 1] <= w) ++c;
        const int local = w - ctl->pairBase[c];
        const int tp    = ctl->tpc[c];
        const int ti    = local / tp;
        const int tj    = local - ti * tp;
        const int n     = ctl->counts[c];
        const int start = ctl->starts[c];
        const int i0    = ti * TS;
        const int j0    = tj * TS;

        // relative quad bases within the class
        const int r0 = i0 + 4 * qb;
        const int r1 = i0 + 4 * qb + 32;
        const int c0 = j0 + 4 * qb;
        const int c1 = j0 + 4 * qb + 32;

        vfloat4 vPr0, vPr1, vTr0, vTr1, vPc0, vPc1, vTc0, vTc1;

        auto load_quad = [&](long off, int rb, vfloat4& vP, vfloat4& vT) {
            if (rb + 3 < n) {
                vP = *(const vfloat4*)&P[off + start + rb];
                vT = *(const vfloat4*)&T[off + start + rb];
            } else {
                int a0 = start + min(rb,     n - 1);
                int a1 = start + min(rb + 1, n - 1);
                int a2 = start + min(rb + 2, n - 1);
                int a3 = start + min(rb + 3, n - 1);
                vP = (vfloat4){P[off + a0], P[off + a1], P[off + a2], P[off + a3]};
                vT = (vfloat4){T[off + a0], T[off + a1], T[off + a2], T[off + a3]};
            }
        };
        auto issue_loads = [&](int dcc) {
            const long off = (long)(dcc + sd) * (long)V;
            load_quad(off, r0, vPr0, vTr0);
            load_quad(off, r1, vPr1, vTr1);
            load_quad(off, c0, vPc0, vTc0);
            load_quad(off, c1, vPc1, vTc1);
        };

        float dpp[4][4], dtt[4][4], dpt[4][4];
        #pragma unroll
        for (int a = 0; a < 4; ++a)
            #pragma unroll
            for (int b = 0; b < 4; ++b) { dpp[a][b] = 0.f; dtt[a][b] = 0.f; dpt[a][b] = 0.f; }

        issue_loads(0);

        #pragma unroll 1
        for (int dc = 0; dc < D; dc += CH) {
            __syncthreads();   // previous chunk's LDS reads (and wsum) complete
            #pragma unroll
            for (int k = 0; k < 4; ++k) {
                sPr[4*qb +      k][sd] = vPr0[k];
                sPr[4*qb + 32 + k][sd] = vPr1[k];
                sTr[4*qb +      k][sd] = vTr0[k];
                sTr[4*qb + 32 + k][sd] = vTr1[k];
                sPc[4*qb +      k][sd] = vPc0[k];
                sPc[4*qb + 32 + k][sd] = vPc1[k];
                sTc[4*qb +      k][sd] = vTc0[k];
                sTc[4*qb + 32 + k][sd] = vTc1[k];
            }
            __syncthreads();
            if (dc + CH < D)
                issue_loads(dc + CH);   // prefetch next chunk; overlaps compute

            // NOT unrolled: one iteration's operands (~16 float4) live at once
            #pragma unroll 1
            for (int dg = 0; dg < CH; dg += 4) {
                // phase A: predict rows x predict cols -> dpp
                float4 rP[4], cX[4];
                #pragma unroll
                for (int a = 0; a < 4; ++a) {
                    rP[a] = *(const float4*)&sPr[ty + 16*a][dg];
                    cX[a] = *(const float4*)&sPc[tx + 16*a][dg];
                }
                #pragma unroll
                for (int a = 0; a < 4; ++a)
                    #pragma unroll
                    for (int b = 0; b < 4; ++b)
                        dpp[a][b] += rP[a].x*cX[b].x + rP[a].y*cX[b].y
                                   + rP[a].z*cX[b].z + rP[a].w*cX[b].w;

                // phase B: predict rows x target cols -> dpt (cX reloaded)
                #pragma unroll
                for (int b = 0; b < 4; ++b)
                    cX[b] = *(const float4*)&sTc[tx + 16*b][dg];
                #pragma unroll
                for (int a = 0; a < 4; ++a)
                    #pragma unroll
                    for (int b = 0; b < 4; ++b)
                        dpt[a][b] += rP[a].x*cX[b].x + rP[a].y*cX[b].y
                                   + rP[a].z*cX[b].z + rP[a].w*cX[b].w;

                // phase C: target rows x target cols -> dtt (rP reloaded)
                #pragma unroll
                for (int a = 0; a < 4; ++a)
                    rP[a] = *(const float4*)&sTr[ty + 16*a][dg];
                #pragma unroll
                for (int a = 0; a < 4; ++a)
                    #pragma unroll
                    for (int b = 0; b < 4; ++b)
                        dtt[a][b] += rP[a].x*cX[b].x + rP[a].y*cX[b].y
                                   + rP[a].z*cX[b].z + rP[a].w*cX[b].w;
            }
        }

        // epilogue: distances via Gram form, 6-bandwidth RBF sum (masked)
        float total = 0.0f;
        #pragma unroll
        for (int a = 0; a < 4; ++a) {
            const int ii = i0 + ty + 16*a;
            if (ii < n) {
                const float nPi = normP[start + ii];
                const float nTi = normT[start + ii];
                #pragma unroll
                for (int b = 0; b < 4; ++b) {
                    const int jj = j0 + tx + 16*b;
                    if (jj < n) {
                        const float nPj = normP[start + jj];
                        const float nTj = normT[start + jj];
                        float Dpp = nPi + nPj - 2.0f * dpp[a][b];
                        float Dtt = nTi + nTj - 2.0f * dtt[a][b];
                        float Dpt = nPi + nTj - 2.0f * dpt[a][b];
                        #pragma unroll
                        for (int s = 0; s < 6; ++s) {
                            total += __expf(invs[s] * Dpp)
                                   + __expf(invs[s] * Dtt)
                                   - 2.0f * __expf(invs[s] * Dpt);
                        }
                    }
                }
            }
        }

        // wave shuffle reduce (width 64), 4 wave leaders via LDS, 1 atomic
        #pragma unroll
        for (int off = 32; off > 0; off >>= 1)
            total += __shfl_down(total, off, 64);
        if ((t & 63) == 0) wsum[t >> 6] = total;
        __syncthreads();
        if (t == 0)
            atomicAdd(&classSum[c], wsum[0] + wsum[1] + wsum[2] + wsum[3]);
    }
}

// ---------------- Kernel 3: finalize scalar loss ----------------------------
__global__ void finalize_kernel(const int* __restrict__ counts,
                                const float* __restrict__ classSum,
                                float* __restrict__ out) {
    if (threadIdx.x == 0) {
        float loss = 0.0f;
        int k = 0;
        for (int c = 0; c < NCLS; ++c) {
            int n = counts[c];
            if (n > 0) {
                ++k;
                float fn    = (float)n;
                float denom = fmaxf(2.0f * fn * fn, 1.0f);
                float l     = classSum[c] / denom;
                if (l > 0.0f) loss += sqrtf(l);
            }
        }
        out[0] = (k > 0) ? (loss / (float)k) : 0.0f;
    }
}

extern "C" void kernel_launch(void* const* d_in, const int* in_sizes, int n_in,
                              void* d_out, int out_size, void* d_ws, size_t ws_size,
                              hipStream_t stream) {
    const float* predict = (const float*)d_in[0];
    const float* target  = (const float*)d_in[1];
    const int*   gt      = (const int*)d_in[2];
    // d_in[3] = ignore_mask: all-True, unused by the reference math.

    const int V = in_sizes[2];        // B*H*W = 4096
    const int D = in_sizes[0] / V;    // C = 128

    Ctl* ctl = (Ctl*)d_ws;
    size_t normOff = (sizeof(Ctl) + 15) & ~(size_t)15;
    float* normP = (float*)((char*)d_ws + normOff);
    float* normT = normP + V;
    float* classSum = (float*)((char*)d_ws + offsetof(Ctl, classSum));

    int nbNorm = (V + PIXB - 1) / PIXB;
    prep_kernel<<<nbNorm + 1, 256, 0, stream>>>(predict, target, gt, V, D,
                                                ctl, normP, normT, nbNorm);

    mmd_kernel<<<NB, 256, 0, stream>>>(predict, target, V, D, ctl,
                                       normP, normT, classSum);

    finalize_kernel<<<1, 64, 0, stream>>>(ctl->counts, classSum, (float*)d_out);
}